// Round 7
// baseline (10272.764 us; speedup 1.0000x reference)
//
#include <hip/hip_runtime.h>
#include <math.h>

#define NN 10000
#define EE 320000
#define INC 64
#define HH 128
#define G4 512

typedef short short8 __attribute__((ext_vector_type(8)));
typedef float f32x4 __attribute__((ext_vector_type(4)));

__device__ __forceinline__ float sigm(float x) { return 1.f / (1.f + __expf(-x)); }
__device__ __forceinline__ float tanh_fast(float x) { return 1.f - 2.f / (1.f + __expf(2.f * x)); }

// fp32 -> bf16 round-to-nearest-even
__device__ __forceinline__ unsigned short f2bf(float f) {
    unsigned u = __float_as_uint(f);
    unsigned r = u + 0x7FFFu + ((u >> 16) & 1u);
    return (unsigned short)(r >> 16);
}

// ---------------- init: zero bn stats (both layers) ----------------
__global__ void k_init(float* stats) {
    int i = blockIdx.x * 256 + threadIdx.x;
    if (i < 512) stats[i] = 0.f;
}

// ---------------- broadcast bias into agg buffer ----------------
__global__ void k_bias_bcast(float* __restrict__ out, const float* __restrict__ b) {
    int i = blockIdx.x * 256 + threadIdx.x;
    if (i < NN * HH) out[i] = b[i & (HH - 1)];
}

// ---------------- C[M,128] = A[M,K] @ B[K,128], K in {64,128} ----------------
__global__ __launch_bounds__(256) void k_gemm_ab(const float* __restrict__ A,
                                                 const float* __restrict__ B,
                                                 float* __restrict__ C,
                                                 int M, int K, int kshift) {
    __shared__ float Alds[32 * 129];
    int tid = threadIdx.x;
    int m0 = blockIdx.x * 32;
    for (int i = tid; i < 32 * K; i += 256) {
        int r = i >> kshift;
        int k = i & (K - 1);
        int m = m0 + r;
        Alds[r * 129 + k] = (m < M) ? A[m * K + k] : 0.f;
    }
    __syncthreads();
    int r = tid >> 3;
    int cg = (tid & 7) * 16;
    float acc[16];
#pragma unroll
    for (int j = 0; j < 16; j++) acc[j] = 0.f;
#pragma unroll 4
    for (int k = 0; k < K; ++k) {
        float a = Alds[r * 129 + k];
        const float4* Brow = (const float4*)(B + k * HH + cg);
        float4 b0 = Brow[0], b1 = Brow[1], b2 = Brow[2], b3 = Brow[3];
        acc[0]  = fmaf(a, b0.x, acc[0]);  acc[1]  = fmaf(a, b0.y, acc[1]);
        acc[2]  = fmaf(a, b0.z, acc[2]);  acc[3]  = fmaf(a, b0.w, acc[3]);
        acc[4]  = fmaf(a, b1.x, acc[4]);  acc[5]  = fmaf(a, b1.y, acc[5]);
        acc[6]  = fmaf(a, b1.z, acc[6]);  acc[7]  = fmaf(a, b1.w, acc[7]);
        acc[8]  = fmaf(a, b2.x, acc[8]);  acc[9]  = fmaf(a, b2.y, acc[9]);
        acc[10] = fmaf(a, b2.z, acc[10]); acc[11] = fmaf(a, b2.w, acc[11]);
        acc[12] = fmaf(a, b3.x, acc[12]); acc[13] = fmaf(a, b3.y, acc[13]);
        acc[14] = fmaf(a, b3.z, acc[14]); acc[15] = fmaf(a, b3.w, acc[15]);
    }
    int m = m0 + r;
    if (m < M) {
        float4* Crow = (float4*)(C + m * HH + cg);
        Crow[0] = make_float4(acc[0], acc[1], acc[2], acc[3]);
        Crow[1] = make_float4(acc[4], acc[5], acc[6], acc[7]);
        Crow[2] = make_float4(acc[8], acc[9], acc[10], acc[11]);
        Crow[3] = make_float4(acc[12], acc[13], acc[14], acc[15]);
    }
}

// ---------------- X[M][128 feat][4 gate] = A[M,128] @ B[512,128]^T + biases ----------------
__global__ __launch_bounds__(256) void k_gemm_abt(const float* __restrict__ A,
                                                   const float* __restrict__ B,
                                                   const float* __restrict__ bias0,
                                                   const float* __restrict__ bias1,
                                                   float* __restrict__ C, int M) {
    __shared__ float Alds[32 * 132];
    int tid = threadIdx.x;
    int m0 = blockIdx.x * 32;
    for (int i = tid; i < 32 * 128; i += 256) {
        int r = i >> 7;
        int k = i & 127;
        int m = m0 + r;
        Alds[r * 132 + k] = (m < M) ? A[m * 128 + k] : 0.f;
    }
    __syncthreads();
    int r = tid >> 3;
    int f0 = blockIdx.y * 16 + (tid & 7) * 2;   // 2 features per thread
    float acc[2][4];
#pragma unroll
    for (int fi = 0; fi < 2; fi++)
#pragma unroll
        for (int gt = 0; gt < 4; gt++) acc[fi][gt] = 0.f;
    const float* a_ptr = &Alds[r * 132];
#pragma unroll 8
    for (int k4 = 0; k4 < 32; ++k4) {
        float4 a = *(const float4*)(a_ptr + 4 * k4);
#pragma unroll
        for (int fi = 0; fi < 2; fi++) {
#pragma unroll
            for (int gt = 0; gt < 4; gt++) {
                float4 b = *(const float4*)(B + (128 * gt + f0 + fi) * 128 + 4 * k4);
                acc[fi][gt] = fmaf(a.x, b.x, acc[fi][gt]);
                acc[fi][gt] = fmaf(a.y, b.y, acc[fi][gt]);
                acc[fi][gt] = fmaf(a.z, b.z, acc[fi][gt]);
                acc[fi][gt] = fmaf(a.w, b.w, acc[fi][gt]);
            }
        }
    }
    int m = m0 + r;
    if (m < M) {
#pragma unroll
        for (int fi = 0; fi < 2; fi++) {
            int f = f0 + fi;
            float4 v;
            v.x = acc[fi][0] + bias0[f]       + bias1[f];
            v.y = acc[fi][1] + bias0[128 + f] + bias1[128 + f];
            v.z = acc[fi][2] + bias0[256 + f] + bias1[256 + f];
            v.w = acc[fi][3] + bias0[384 + f] + bias1[384 + f];
            *(float4*)(C + m * 512 + f * 4) = v;
        }
    }
}

// ---------------- scatter: agg[dst] += h[src]*ew ----------------
__global__ void k_scatter(const float* __restrict__ h, const int* __restrict__ ei,
                          const float* __restrict__ ew, float* agg) {
    int gid = blockIdx.x * 256 + threadIdx.x;
    if (gid >= EE * 32) return;
    int e = gid >> 5;
    int q = (gid & 31) << 2;
    int src = ei[e];
    int dst = ei[EE + e];
    float w = ew[e];
    float4 v = *(const float4*)(h + src * 128 + q);
    float* p = agg + dst * 128 + q;
    atomicAdd(p + 0, v.x * w);
    atomicAdd(p + 1, v.y * w);
    atomicAdd(p + 2, v.z * w);
    atomicAdd(p + 3, v.w * w);
}

// ---------------- per-feature sum / sumsq ----------------
__global__ __launch_bounds__(256) void k_bn_stats(const float* __restrict__ x,
                                                   float* __restrict__ stats) {
    int c = threadIdx.x & 127;
    int half = threadIdx.x >> 7;
    float s = 0.f, q = 0.f;
    for (int r = blockIdx.x * 2 + half; r < NN; r += gridDim.x * 2) {
        float v = x[r * HH + c];
        s += v;
        q = fmaf(v, v, q);
    }
    __shared__ float ls[256], lq[256];
    ls[threadIdx.x] = s;
    lq[threadIdx.x] = q;
    __syncthreads();
    if (half == 0) {
        atomicAdd(&stats[c], s + ls[128 + c]);
        atomicAdd(&stats[128 + c], q + lq[128 + c]);
    }
}

// ---------------- bn + relu elementwise ----------------
__global__ void k_bn_relu(const float* __restrict__ x, const float* __restrict__ stats,
                          const float* __restrict__ g, const float* __restrict__ be,
                          float* __restrict__ out) {
    int i = blockIdx.x * 256 + threadIdx.x;
    if (i >= NN * HH) return;
    int c = i & 127;
    float mean = stats[c] * (1.f / NN);
    float var = fmaf(-mean, mean, stats[128 + c] * (1.f / NN));
    float alpha = g[c] * rsqrtf(var + 1e-5f);
    float beta = fmaf(-mean, alpha, be[c]);
    out[i] = fmaxf(0.f, fmaf(x[i], alpha, beta));
}

// ---------------- sequential bidirectional LSTM scan ----------------
// R7: 16 waves per direction (1024-thread block, 4 waves/SIMD). R5->R6 showed the
// step is LATENCY-bound (same per-SIMD MFMA, half the VALU -> slower), so add
// waves to overlap chains. Per-SIMD matrix work constant (32 MFMAs = the
// structural floor: 512x128 matvec needs >=128 MFMAs/dir since each MFMA ingests
// only 512 fresh weights; N-columns are inherently wasted for matvec).
// Wave w owns 2 M-tiles = features [8w, 8w+8) x 4 gates, gate-interleaved rows:
// A row mr of tile tl = Whh row 128*(mr&3) + 8w + 4*tl + (mr>>2). D layout
// (col=n=lane&15, row=4q+reg, q=lane>>4) => lane (q,n) reg r = gate r of feature
// 8w + 4*tl + q. Lane selects tl = n&1 (4 cndmasks) -> ONE activation chain/wave.
// Writers: n<2. One lgkm-only barrier/step, static ping-pong h_bf, walking ptrs,
// xproj [t][f][gate] so each lane's 4 gates = one dwordx4, depth-2 prefetch.
__global__ __launch_bounds__(1024, 1) void k_lstm(const float* __restrict__ xpf,
                                                   const float* __restrict__ xpb,
                                                   const float* __restrict__ whf,
                                                   const float* __restrict__ whb,
                                                   float* __restrict__ hf,
                                                   float* __restrict__ hb) {
    const int dir = blockIdx.x;
    const float* __restrict__ xp = dir ? xpb : xpf;
    const float* __restrict__ Whh = dir ? whb : whf;
    float* __restrict__ hsp = dir ? hb : hf;
    const int j = threadIdx.x;
    const int lane = j & 63;
    const int w = j >> 6;            // wave id 0..15 -> features [8w, 8w+8)
    const int q = lane >> 4;         // k-group for A/B load; D row-group
    const int n = lane & 15;         // A tile-row; D col
    const int tlsel = n & 1;         // selected M-tile
    const int f1 = 8 * w + 4 * tlsel + q;   // this lane's feature
    const bool writer = (n < 2);

    // ---- A fragments: 2 tiles x 4 k-steps, gate-interleaved rows, bf16, pinned
    short8 af[2][4];
#pragma unroll
    for (int tl = 0; tl < 2; ++tl) {
#pragma unroll
        for (int kt = 0; kt < 4; ++kt) {
            const float* wp = Whh + (128 * (n & 3) + 8 * w + 4 * tl + (n >> 2)) * 128
                              + 32 * kt + 8 * q;
            float4 q0 = *(const float4*)wp;
            float4 q1 = *(const float4*)(wp + 4);
            short8 a;
            a[0] = (short)f2bf(q0.x); a[1] = (short)f2bf(q0.y);
            a[2] = (short)f2bf(q0.z); a[3] = (short)f2bf(q0.w);
            a[4] = (short)f2bf(q1.x); a[5] = (short)f2bf(q1.y);
            a[6] = (short)f2bf(q1.z); a[7] = (short)f2bf(q1.w);
            af[tl][kt] = a;
        }
    }

    __shared__ __align__(16) short h_bf[2][128];
    if (j < 128) h_bf[0][j] = 0;
    float c = 0.f;
    __syncthreads();

    // walking pointers
    const int xinc = dir ? -G4 : G4;
    const int hinc = dir ? -HH : HH;
    const float* xptr = xp + (dir ? (NN - 1) : 0) * G4 + f1 * 4;
    float* hptr = hsp + (dir ? (NN - 1) : 0) * HH + f1;

    f32x4 xE = *(const f32x4*)xptr; xptr += xinc;
    f32x4 xO = *(const f32x4*)xptr; xptr += xinc;

    const bool b0 = (n & 1);

#define LSTM_STEP(BUFR, BUFW, XV)                                                        \
    {                                                                                    \
        const short8* hb8 = (const short8*)h_bf[BUFR];                                   \
        short8 bf0 = hb8[q], bf1 = hb8[4 + q], bf2 = hb8[8 + q], bf3 = hb8[12 + q];      \
        f32x4 acc[2];                                                                    \
        acc[0] = (f32x4){0.f, 0.f, 0.f, 0.f};                                            \
        acc[1] = (f32x4){0.f, 0.f, 0.f, 0.f};                                            \
        _Pragma("unroll")                                                                \
        for (int tl = 0; tl < 2; ++tl)                                                   \
            acc[tl] = __builtin_amdgcn_mfma_f32_16x16x32_bf16(af[tl][0], bf0, acc[tl], 0, 0, 0); \
        _Pragma("unroll")                                                                \
        for (int tl = 0; tl < 2; ++tl)                                                   \
            acc[tl] = __builtin_amdgcn_mfma_f32_16x16x32_bf16(af[tl][1], bf1, acc[tl], 0, 0, 0); \
        _Pragma("unroll")                                                                \
        for (int tl = 0; tl < 2; ++tl)                                                   \
            acc[tl] = __builtin_amdgcn_mfma_f32_16x16x32_bf16(af[tl][2], bf2, acc[tl], 0, 0, 0); \
        _Pragma("unroll")                                                                \
        for (int tl = 0; tl < 2; ++tl)                                                   \
            acc[tl] = __builtin_amdgcn_mfma_f32_16x16x32_bf16(af[tl][3], bf3, acc[tl], 0, 0, 0); \
        float gv[4];                                                                     \
        _Pragma("unroll")                                                                \
        for (int r = 0; r < 4; ++r) gv[r] = b0 ? acc[1][r] : acc[0][r];                  \
        float ig = sigm(gv[0] + (XV)[0]);                                                \
        float fg = sigm(gv[1] + (XV)[1]);                                                \
        float cg = tanh_fast(gv[2] + (XV)[2]);                                           \
        float og = sigm(gv[3] + (XV)[3]);                                                \
        c = fmaf(fg, c, ig * cg);                                                        \
        float h = og * tanh_fast(c);                                                     \
        if (writer) {                                                                    \
            *hptr = h;                                                                   \
            h_bf[BUFW][f1] = (short)f2bf(h);                                             \
        }                                                                                \
        hptr += hinc;                                                                    \
    }

    for (int s = 0; s < NN; s += 2) {
        f32x4 xE2 = *(const f32x4*)xptr; xptr += xinc;   // prefetch s+2
        LSTM_STEP(0, 1, xE)
        asm volatile("s_waitcnt lgkmcnt(0)\n\ts_barrier" ::: "memory");

        f32x4 xO2 = *(const f32x4*)xptr; xptr += xinc;   // prefetch s+3
        LSTM_STEP(1, 0, xO)
        asm volatile("s_waitcnt lgkmcnt(0)\n\ts_barrier" ::: "memory");

        xE = xE2;
        xO = xO2;
    }
#undef LSTM_STEP
}

// ---------------- out = [hf|hb] @ Wo + bo ----------------
__global__ void k_out(const float* __restrict__ hf, const float* __restrict__ hb,
                      const float* __restrict__ Wo, const float* __restrict__ bo,
                      float* __restrict__ out) {
    int idx = blockIdx.x * 256 + threadIdx.x;
    if (idx >= NN * 12) return;
    int n = idx / 12;
    int p = idx - n * 12;
    float acc = bo[p];
    const float4* hfr = (const float4*)(hf + n * 128);
    const float4* hbr = (const float4*)(hb + n * 128);
#pragma unroll 4
    for (int k4 = 0; k4 < 32; ++k4) {
        float4 v = hfr[k4];
        acc = fmaf(v.x, Wo[(4 * k4 + 0) * 12 + p], acc);
        acc = fmaf(v.y, Wo[(4 * k4 + 1) * 12 + p], acc);
        acc = fmaf(v.z, Wo[(4 * k4 + 2) * 12 + p], acc);
        acc = fmaf(v.w, Wo[(4 * k4 + 3) * 12 + p], acc);
    }
#pragma unroll 4
    for (int k4 = 0; k4 < 32; ++k4) {
        float4 v = hbr[k4];
        acc = fmaf(v.x, Wo[(128 + 4 * k4 + 0) * 12 + p], acc);
        acc = fmaf(v.y, Wo[(128 + 4 * k4 + 1) * 12 + p], acc);
        acc = fmaf(v.z, Wo[(128 + 4 * k4 + 2) * 12 + p], acc);
        acc = fmaf(v.w, Wo[(128 + 4 * k4 + 3) * 12 + p], acc);
    }
    out[idx] = acc;
}

extern "C" void kernel_launch(void* const* d_in, const int* in_sizes, int n_in,
                              void* d_out, int out_size, void* d_ws, size_t ws_size,
                              hipStream_t stream) {
    const float* x    = (const float*)d_in[0];
    const int*   ei   = (const int*)d_in[1];
    const float* ew   = (const float*)d_in[2];
    const float* W1   = (const float*)d_in[3];
    const float* b1   = (const float*)d_in[4];
    const float* g1   = (const float*)d_in[5];
    const float* be1  = (const float*)d_in[6];
    const float* W2   = (const float*)d_in[7];
    const float* b2   = (const float*)d_in[8];
    const float* g2   = (const float*)d_in[9];
    const float* be2  = (const float*)d_in[10];
    const float* Wihf = (const float*)d_in[11];
    const float* Whhf = (const float*)d_in[12];
    const float* bihf = (const float*)d_in[13];
    const float* bhhf = (const float*)d_in[14];
    const float* Wihb = (const float*)d_in[15];
    const float* Whhb = (const float*)d_in[16];
    const float* bihb = (const float*)d_in[17];
    const float* bhhb = (const float*)d_in[18];
    const float* Wo   = (const float*)d_in[21];
    const float* bo   = (const float*)d_in[22];
    float* out = (float*)d_out;
    float* ws  = (float*)d_ws;

    float* bufA  = ws;                 // 1,280,000
    float* bufB  = ws + 1280000;       // 1,280,000
    float* bufC  = ws + 2560000;       // 1,280,000
    float* stats = ws + 3840000;       // 512
    float* Xf    = ws + 3840512;       // 5,120,000
    float* Xb    = ws + 8960512;       // 5,120,000
    float* hfp   = ws + 14080512;      // 1,280,000
    float* hbp   = ws + 15360512;      // 1,280,000

    const int nElem = NN * HH;
    const int gElem = (nElem + 255) / 256;

    k_init<<<2, 256, 0, stream>>>(stats);

    // ---- GCN layer 1 ----
    k_gemm_ab<<<313, 256, 0, stream>>>(x, W1, bufA, NN, 64, 6);
    k_bias_bcast<<<gElem, 256, 0, stream>>>(bufB, b1);
    k_scatter<<<(EE * 32) / 256, 256, 0, stream>>>(bufA, ei, ew, bufB);
    k_bn_stats<<<100, 256, 0, stream>>>(bufB, stats);
    k_bn_relu<<<gElem, 256, 0, stream>>>(bufB, stats, g1, be1, bufC);

    // ---- GCN layer 2 ----
    k_gemm_ab<<<313, 256, 0, stream>>>(bufC, W2, bufA, NN, 128, 7);
    k_bias_bcast<<<gElem, 256, 0, stream>>>(bufB, b2);
    k_scatter<<<(EE * 32) / 256, 256, 0, stream>>>(bufA, ei, ew, bufB);
    k_bn_stats<<<100, 256, 0, stream>>>(bufB, stats + 256);
    k_bn_relu<<<gElem, 256, 0, stream>>>(bufB, stats + 256, g2, be2, bufC);

    // ---- LSTM input projections (batched GEMMs, biases folded, permuted layout) ----
    dim3 gx(313, 8);
    k_gemm_abt<<<gx, 256, 0, stream>>>(bufC, Wihf, bihf, bhhf, Xf, NN);
    k_gemm_abt<<<gx, 256, 0, stream>>>(bufC, Wihb, bihb, bhhb, Xb, NN);

    // ---- sequential bidirectional scan (both directions concurrent) ----
    k_lstm<<<2, 1024, 0, stream>>>(Xf, Xb, Whhf, Whhb, hfp, hbp);

    // ---- attention is identity (softmax over singleton axis); final matmul ----
    k_out<<<(NN * 12 + 255) / 256, 256, 0, stream>>>(hfp, hbp, Wo, bo, out);
}

// Round 8
// 6632.729 us; speedup vs baseline: 1.5488x; 1.5488x over previous
//
#include <hip/hip_runtime.h>
#include <math.h>

#define NN 10000
#define EE 320000
#define INC 64
#define HH 128
#define G4 512

typedef short short8 __attribute__((ext_vector_type(8)));
typedef float f32x4 __attribute__((ext_vector_type(4)));

__device__ __forceinline__ float sigm(float x) { return 1.f / (1.f + __expf(-x)); }
__device__ __forceinline__ float tanh_fast(float x) { return 1.f - 2.f / (1.f + __expf(2.f * x)); }

// fp32 -> bf16 round-to-nearest-even
__device__ __forceinline__ unsigned short f2bf(float f) {
    unsigned u = __float_as_uint(f);
    unsigned r = u + 0x7FFFu + ((u >> 16) & 1u);
    return (unsigned short)(r >> 16);
}

// ---------------- zero stats + edge counters ----------------
__global__ void k_zero(float* stats, int* cnt) {
    int i = blockIdx.x * 256 + threadIdx.x;
    if (i < 512) stats[i] = 0.f;
    if (i < NN) cnt[i] = 0;
}

// ---------------- histogram of dst ----------------
__global__ void k_hist(const int* __restrict__ ei, int* __restrict__ cnt) {
    int e = blockIdx.x * 256 + threadIdx.x;
    if (e < EE) atomicAdd(&cnt[ei[EE + e]], 1);
}

// ---------------- exclusive scan of cnt -> off; re-zero cnt ----------------
__global__ __launch_bounds__(1024) void k_scan(int* __restrict__ cnt, int* __restrict__ off) {
    __shared__ int part[1024];
    int i = threadIdx.x;
    int base = i * 10;
    int s = 0;
#pragma unroll
    for (int k = 0; k < 10; ++k) { int idx = base + k; if (idx < NN) s += cnt[idx]; }
    part[i] = s;
    __syncthreads();
    for (int d = 1; d < 1024; d <<= 1) {   // Hillis-Steele inclusive scan
        int v = (i >= d) ? part[i - d] : 0;
        __syncthreads();
        part[i] += v;
        __syncthreads();
    }
    int run = (i > 0) ? part[i - 1] : 0;
#pragma unroll
    for (int k = 0; k < 10; ++k) {
        int idx = base + k;
        if (idx < NN) { off[idx] = run; run += cnt[idx]; cnt[idx] = 0; }
    }
    if (i == 1023) off[NN] = part[1023];
}

// ---------------- fill CSR edge ids ----------------
__global__ void k_fill(const int* __restrict__ ei, const int* __restrict__ off,
                       int* __restrict__ cnt, int* __restrict__ csr) {
    int e = blockIdx.x * 256 + threadIdx.x;
    if (e >= EE) return;
    int dst = ei[EE + e];
    int pos = off[dst] + atomicAdd(&cnt[dst], 1);
    csr[pos] = e;
}

// ---------------- C[M,128] = A[M,K] @ B[K,128], K in {64,128} (fp32) ----------------
__global__ __launch_bounds__(256) void k_gemm_ab(const float* __restrict__ A,
                                                 const float* __restrict__ B,
                                                 float* __restrict__ C,
                                                 int M, int K, int kshift) {
    __shared__ float Alds[32 * 129];
    int tid = threadIdx.x;
    int m0 = blockIdx.x * 32;
    for (int i = tid; i < 32 * K; i += 256) {
        int r = i >> kshift;
        int k = i & (K - 1);
        int m = m0 + r;
        Alds[r * 129 + k] = (m < M) ? A[m * K + k] : 0.f;
    }
    __syncthreads();
    int r = tid >> 3;
    int cg = (tid & 7) * 16;
    float acc[16];
#pragma unroll
    for (int j = 0; j < 16; j++) acc[j] = 0.f;
#pragma unroll 4
    for (int k = 0; k < K; ++k) {
        float a = Alds[r * 129 + k];
        const float4* Brow = (const float4*)(B + k * HH + cg);
        float4 b0 = Brow[0], b1 = Brow[1], b2 = Brow[2], b3 = Brow[3];
        acc[0]  = fmaf(a, b0.x, acc[0]);  acc[1]  = fmaf(a, b0.y, acc[1]);
        acc[2]  = fmaf(a, b0.z, acc[2]);  acc[3]  = fmaf(a, b0.w, acc[3]);
        acc[4]  = fmaf(a, b1.x, acc[4]);  acc[5]  = fmaf(a, b1.y, acc[5]);
        acc[6]  = fmaf(a, b1.z, acc[6]);  acc[7]  = fmaf(a, b1.w, acc[7]);
        acc[8]  = fmaf(a, b2.x, acc[8]);  acc[9]  = fmaf(a, b2.y, acc[9]);
        acc[10] = fmaf(a, b2.z, acc[10]); acc[11] = fmaf(a, b2.w, acc[11]);
        acc[12] = fmaf(a, b3.x, acc[12]); acc[13] = fmaf(a, b3.y, acc[13]);
        acc[14] = fmaf(a, b3.z, acc[14]); acc[15] = fmaf(a, b3.w, acc[15]);
    }
    int m = m0 + r;
    if (m < M) {
        float4* Crow = (float4*)(C + m * HH + cg);
        Crow[0] = make_float4(acc[0], acc[1], acc[2], acc[3]);
        Crow[1] = make_float4(acc[4], acc[5], acc[6], acc[7]);
        Crow[2] = make_float4(acc[8], acc[9], acc[10], acc[11]);
        Crow[3] = make_float4(acc[12], acc[13], acc[14], acc[15]);
    }
}

// ---------------- CSR gather: agg[n] = b + sum_e h[src]*w; fused BN stats ----------------
__global__ __launch_bounds__(256) void k_gather(const float* __restrict__ h,
                                                 const int* __restrict__ ei,
                                                 const float* __restrict__ ew,
                                                 const int* __restrict__ off,
                                                 const int* __restrict__ csr,
                                                 const float* __restrict__ bias,
                                                 float* __restrict__ agg,
                                                 float* __restrict__ stats) {
    int tid = threadIdx.x;
    int node = blockIdx.x * 8 + (tid >> 5);
    int q32 = tid & 31;
    const f32x4 bv = *(const f32x4*)(bias + q32 * 4);
    f32x4 acc = bv;
    int beg = off[node], end = off[node + 1];
    for (int i = beg; i < end; ++i) {
        int e = csr[i];
        int src = ei[e];
        float w = ew[e];
        f32x4 v = *(const f32x4*)(h + src * 128 + q32 * 4);
        acc[0] = fmaf(v[0], w, acc[0]);
        acc[1] = fmaf(v[1], w, acc[1]);
        acc[2] = fmaf(v[2], w, acc[2]);
        acc[3] = fmaf(v[3], w, acc[3]);
    }
    *(f32x4*)(agg + node * 128 + q32 * 4) = acc;

    // fused per-feature sum/sumsq (block partial -> atomics)
    __shared__ f32x4 ls[256], lq[256];
    ls[tid] = acc;
    lq[tid] = acc * acc;
    __syncthreads();
    if (tid < 32) {
        f32x4 s = ls[tid], q = lq[tid];
#pragma unroll
        for (int g = 1; g < 8; ++g) { s += ls[g * 32 + tid]; q += lq[g * 32 + tid]; }
#pragma unroll
        for (int c = 0; c < 4; ++c) {
            atomicAdd(&stats[tid * 4 + c], s[c]);
            atomicAdd(&stats[128 + tid * 4 + c], q[c]);
        }
    }
}

// ---------------- bn + relu elementwise (optional bf16 side-output) ----------------
__global__ void k_bn_relu(const float* __restrict__ x, const float* __restrict__ stats,
                          const float* __restrict__ g, const float* __restrict__ be,
                          float* __restrict__ out, unsigned short* __restrict__ outbf) {
    int i = blockIdx.x * 256 + threadIdx.x;
    if (i >= NN * HH) return;
    int c = i & 127;
    float mean = stats[c] * (1.f / NN);
    float var = fmaf(-mean, mean, stats[128 + c] * (1.f / NN));
    float alpha = g[c] * rsqrtf(var + 1e-5f);
    float beta = fmaf(-mean, alpha, be[c]);
    float r = fmaxf(0.f, fmaf(x[i], alpha, beta));
    out[i] = r;
    if (outbf) outbf[i] = f2bf(r);
}

// ---------------- convert Wih (both dirs) to bf16; sum biases ----------------
__global__ void k_cvtW(const float* __restrict__ Wf, const float* __restrict__ Wb,
                       const float* __restrict__ bif, const float* __restrict__ bhf,
                       const float* __restrict__ bib, const float* __restrict__ bhb,
                       unsigned short* __restrict__ wf, unsigned short* __restrict__ wb,
                       float* __restrict__ bsf, float* __restrict__ bsb) {
    int i = blockIdx.x * 256 + threadIdx.x;
    if (i < 512) bsf[i] = bif[i] + bhf[i];
    else if (i < 1024) bsb[i - 512] = bib[i - 512] + bhb[i - 512];
    else if (i < 1024 + 65536) wf[i - 1024] = f2bf(Wf[i - 1024]);
    else if (i < 1024 + 131072) wb[i - 1024 - 65536] = f2bf(Wb[i - 1024 - 65536]);
}

// ---------------- X[m][f][gate] = A_bf[m,k] @ W_bf[gr,k]^T + bsum  (MFMA, both dirs) ----------------
__global__ __launch_bounds__(256) void k_mm512p(const unsigned short* __restrict__ A,
                                                 const unsigned short* __restrict__ Wfp,
                                                 const unsigned short* __restrict__ Wbp,
                                                 const float* __restrict__ bsf,
                                                 const float* __restrict__ bsb,
                                                 float* __restrict__ Xf,
                                                 float* __restrict__ Xb) {
    const int dir = blockIdx.y;
    const unsigned short* __restrict__ W = dir ? Wbp : Wfp;
    const float* __restrict__ bs = dir ? bsb : bsf;
    float* __restrict__ X = dir ? Xb : Xf;

    __shared__ __align__(16) unsigned short Asub[64 * 128];   // 16 KB
    int tid = threadIdx.x;
    int m0 = blockIdx.x * 64;
    for (int i = tid; i < 1024; i += 256) {     // 64 rows x 16 (8-elem groups)
        int r = i >> 4, kg = i & 15;
        int m = m0 + r;
        short8 v = (short8){0, 0, 0, 0, 0, 0, 0, 0};
        if (m < NN) v = *(const short8*)(A + m * 128 + kg * 8);
        *(short8*)(&Asub[r * 128 + kg * 8]) = v;
    }
    __syncthreads();

    int lane = tid & 63, wv = tid >> 6;
    int q = lane >> 4, n = lane & 15;
    // A-frags: rows 16wv+n, k-group q  (A layout: lane = 16*(k>>3)+m)
    short8 afr[4];
#pragma unroll
    for (int kt = 0; kt < 4; ++kt)
        afr[kt] = *(const short8*)(&Asub[(16 * wv + n) * 128 + kt * 32 + q * 8]);

    for (int nt = 0; nt < 32; ++nt) {
        int gr = nt * 16 + n;
        short8 bfr[4];
#pragma unroll
        for (int kt = 0; kt < 4; ++kt)
            bfr[kt] = *(const short8*)(W + gr * 128 + kt * 32 + q * 8);
        f32x4 acc = (f32x4){0.f, 0.f, 0.f, 0.f};
#pragma unroll
        for (int kt = 0; kt < 4; ++kt)
            acc = __builtin_amdgcn_mfma_f32_16x16x32_bf16(afr[kt], bfr[kt], acc, 0, 0, 0);
        float b = bs[gr];
        int fg4 = (gr & 127) * 4 + (gr >> 7);
#pragma unroll
        for (int r = 0; r < 4; ++r) {
            int m = m0 + 16 * wv + 4 * q + r;
            if (m < NN) X[m * 512 + fg4] = acc[r] + b;
        }
    }
}

// ---------------- sequential bidirectional LSTM scan (exact R5 structure) ----------------
// 8 waves; wave w owns features [16w,16w+16) across all 4 gate types. One feature
// per lane via acc-reg select (R3 lesson); one lgkm-only barrier/step; static
// ping-pong h_bf; walking pointers; xproj [t][f][gate] -> one dwordx4/lane/step.
__global__ __launch_bounds__(512, 1) void k_lstm(const float* __restrict__ xpf,
                                                  const float* __restrict__ xpb,
                                                  const float* __restrict__ whf,
                                                  const float* __restrict__ whb,
                                                  float* __restrict__ hf,
                                                  float* __restrict__ hb) {
    const int dir = blockIdx.x;
    const float* __restrict__ xp = dir ? xpb : xpf;
    const float* __restrict__ Whh = dir ? whb : whf;
    float* __restrict__ hsp = dir ? hb : hf;
    const int j = threadIdx.x;
    const int lane = j & 63;
    const int w = j >> 6;
    const int g16 = lane >> 4;
    const int m = lane & 15;
    const int r2 = m & 3;
    const int f1 = 16 * w + 4 * g16 + r2;
    const bool writer = (m < 4);

    short8 af[4][4];
#pragma unroll
    for (int gt = 0; gt < 4; ++gt) {
#pragma unroll
        for (int kt = 0; kt < 4; ++kt) {
            const float* wp = Whh + (128 * gt + 16 * w + m) * 128 + 32 * kt + 8 * g16;
            float4 q0 = *(const float4*)wp;
            float4 q1 = *(const float4*)(wp + 4);
            short8 a;
            a[0] = (short)f2bf(q0.x); a[1] = (short)f2bf(q0.y);
            a[2] = (short)f2bf(q0.z); a[3] = (short)f2bf(q0.w);
            a[4] = (short)f2bf(q1.x); a[5] = (short)f2bf(q1.y);
            a[6] = (short)f2bf(q1.z); a[7] = (short)f2bf(q1.w);
            af[gt][kt] = a;
        }
    }

    __shared__ __align__(16) short h_bf[2][128];
    if (j < 128) h_bf[0][j] = 0;
    float c = 0.f;
    __syncthreads();

    const int xinc = dir ? -G4 : G4;
    const int hinc = dir ? -HH : HH;
    const float* xptr = xp + (dir ? (NN - 1) : 0) * G4 + f1 * 4;
    float* hptr = hsp + (dir ? (NN - 1) : 0) * HH + f1;

    f32x4 xE = *(const f32x4*)xptr; xptr += xinc;
    f32x4 xO = *(const f32x4*)xptr; xptr += xinc;

#define LSTM_STEP(BUFR, BUFW, XV)                                                        \
    {                                                                                    \
        const short8* hb8 = (const short8*)h_bf[BUFR];                                   \
        short8 bf0 = hb8[g16], bf1 = hb8[4 + g16], bf2 = hb8[8 + g16], bf3 = hb8[12 + g16]; \
        f32x4 acc[4];                                                                    \
        _Pragma("unroll")                                                                \
        for (int gt = 0; gt < 4; ++gt) acc[gt] = (f32x4){0.f, 0.f, 0.f, 0.f};            \
        _Pragma("unroll")                                                                \
        for (int gt = 0; gt < 4; ++gt)                                                   \
            acc[gt] = __builtin_amdgcn_mfma_f32_16x16x32_bf16(af[gt][0], bf0, acc[gt], 0, 0, 0); \
        _Pragma("unroll")                                                                \
        for (int gt = 0; gt < 4; ++gt)                                                   \
            acc[gt] = __builtin_amdgcn_mfma_f32_16x16x32_bf16(af[gt][1], bf1, acc[gt], 0, 0, 0); \
        _Pragma("unroll")                                                                \
        for (int gt = 0; gt < 4; ++gt)                                                   \
            acc[gt] = __builtin_amdgcn_mfma_f32_16x16x32_bf16(af[gt][2], bf2, acc[gt], 0, 0, 0); \
        _Pragma("unroll")                                                                \
        for (int gt = 0; gt < 4; ++gt)                                                   \
            acc[gt] = __builtin_amdgcn_mfma_f32_16x16x32_bf16(af[gt][3], bf3, acc[gt], 0, 0, 0); \
        float gv[4];                                                                     \
        _Pragma("unroll")                                                                \
        for (int r = 0; r < 4; ++r) {                                                    \
            float lo = (r2 & 1) ? acc[r][1] : acc[r][0];                                 \
            float hi = (r2 & 1) ? acc[r][3] : acc[r][2];                                 \
            gv[r] = (r2 & 2) ? hi : lo;                                                  \
        }                                                                                \
        float ig = sigm(gv[0] + (XV)[0]);                                                \
        float fg = sigm(gv[1] + (XV)[1]);                                                \
        float cg = tanh_fast(gv[2] + (XV)[2]);                                           \
        float og = sigm(gv[3] + (XV)[3]);                                                \
        c = fmaf(fg, c, ig * cg);                                                        \
        float h = og * tanh_fast(c);                                                     \
        if (writer) {                                                                    \
            *hptr = h;                                                                   \
            h_bf[BUFW][f1] = (short)f2bf(h);                                             \
        }                                                                                \
        hptr += hinc;                                                                    \
    }

    for (int s = 0; s < NN; s += 2) {
        f32x4 xE2 = *(const f32x4*)xptr; xptr += xinc;
        LSTM_STEP(0, 1, xE)
        asm volatile("s_waitcnt lgkmcnt(0)\n\ts_barrier" ::: "memory");

        f32x4 xO2 = *(const f32x4*)xptr; xptr += xinc;
        LSTM_STEP(1, 0, xO)
        asm volatile("s_waitcnt lgkmcnt(0)\n\ts_barrier" ::: "memory");

        xE = xE2;
        xO = xO2;
    }
#undef LSTM_STEP
}

// ---------------- out = [hf|hb] @ Wo + bo ----------------
__global__ void k_out(const float* __restrict__ hf, const float* __restrict__ hb,
                      const float* __restrict__ Wo, const float* __restrict__ bo,
                      float* __restrict__ out) {
    int idx = blockIdx.x * 256 + threadIdx.x;
    if (idx >= NN * 12) return;
    int n = idx / 12;
    int p = idx - n * 12;
    float acc = bo[p];
    const float4* hfr = (const float4*)(hf + n * 128);
    const float4* hbr = (const float4*)(hb + n * 128);
#pragma unroll 4
    for (int k4 = 0; k4 < 32; ++k4) {
        float4 v = hfr[k4];
        acc = fmaf(v.x, Wo[(4 * k4 + 0) * 12 + p], acc);
        acc = fmaf(v.y, Wo[(4 * k4 + 1) * 12 + p], acc);
        acc = fmaf(v.z, Wo[(4 * k4 + 2) * 12 + p], acc);
        acc = fmaf(v.w, Wo[(4 * k4 + 3) * 12 + p], acc);
    }
#pragma unroll 4
    for (int k4 = 0; k4 < 32; ++k4) {
        float4 v = hbr[k4];
        acc = fmaf(v.x, Wo[(128 + 4 * k4 + 0) * 12 + p], acc);
        acc = fmaf(v.y, Wo[(128 + 4 * k4 + 1) * 12 + p], acc);
        acc = fmaf(v.z, Wo[(128 + 4 * k4 + 2) * 12 + p], acc);
        acc = fmaf(v.w, Wo[(128 + 4 * k4 + 3) * 12 + p], acc);
    }
    out[idx] = acc;
}

extern "C" void kernel_launch(void* const* d_in, const int* in_sizes, int n_in,
                              void* d_out, int out_size, void* d_ws, size_t ws_size,
                              hipStream_t stream) {
    const float* x    = (const float*)d_in[0];
    const int*   ei   = (const int*)d_in[1];
    const float* ew   = (const float*)d_in[2];
    const float* W1   = (const float*)d_in[3];
    const float* b1   = (const float*)d_in[4];
    const float* g1   = (const float*)d_in[5];
    const float* be1  = (const float*)d_in[6];
    const float* W2   = (const float*)d_in[7];
    const float* b2   = (const float*)d_in[8];
    const float* g2   = (const float*)d_in[9];
    const float* be2  = (const float*)d_in[10];
    const float* Wihf = (const float*)d_in[11];
    const float* Whhf = (const float*)d_in[12];
    const float* bihf = (const float*)d_in[13];
    const float* bhhf = (const float*)d_in[14];
    const float* Wihb = (const float*)d_in[15];
    const float* Whhb = (const float*)d_in[16];
    const float* bihb = (const float*)d_in[17];
    const float* bhhb = (const float*)d_in[18];
    const float* Wo   = (const float*)d_in[21];
    const float* bo   = (const float*)d_in[22];
    float* out = (float*)d_out;
    float* ws  = (float*)d_ws;

    // ---- big fp32 buffers (same footprint as R5: 16,640,512 floats) ----
    float* bufA  = ws;                 // 1,280,000  (GEMM out = h)
    float* bufB  = ws + 1280000;       // 1,280,000  (agg)
    float* bufC  = ws + 2560000;       // 1,280,000  (bn_relu out)
    float* stats = ws + 3840000;       // 512
    float* Xf    = ws + 3840512;       // 5,120,000
    float* Xb    = ws + 8960512;       // 5,120,000
    float* hfp   = ws + 14080512;      // 1,280,000
    float* hbp   = ws + 15360512;      // 1,280,000

    // ---- overlay region inside hfp (consumed before k_lstm writes hfp) ----
    unsigned short* cbf  = (unsigned short*)(ws + 14080512);  // 1.28M ushort (640,000 slots)
    unsigned short* wfbf = (unsigned short*)(ws + 14720512);  // 65,536 ushort (32,768 slots)
    unsigned short* wbbf = (unsigned short*)(ws + 14753280);  // 65,536 ushort
    float* bsumf = ws + 14786048;                             // 512
    float* bsumb = ws + 14786560;                             // 512
    int* icnt = (int*)(ws + 14787072);                        // 10,000
    int* ioff = icnt + 10000;                                 // 10,001
    int* icsr = ioff + 10001;                                 // 320,000  (ends < hfp end)

    const int nElem = NN * HH;
    const int gElem = (nElem + 255) / 256;
    const int gEdge = (EE + 255) / 256;

    // ---- CSR build (edge list is input data; rebuilt deterministically each call) ----
    k_zero<<<(NN + 255) / 256, 256, 0, stream>>>(stats, icnt);
    k_hist<<<gEdge, 256, 0, stream>>>(ei, icnt);
    k_scan<<<1, 1024, 0, stream>>>(icnt, ioff);
    k_fill<<<gEdge, 256, 0, stream>>>(ei, ioff, icnt, icsr);
    k_cvtW<<<(132096 + 255) / 256, 256, 0, stream>>>(Wihf, Wihb, bihf, bhhf, bihb, bhhb,
                                                     wfbf, wbbf, bsumf, bsumb);

    // ---- GCN layer 1 ----
    k_gemm_ab<<<313, 256, 0, stream>>>(x, W1, bufA, NN, 64, 6);
    k_gather<<<NN / 8, 256, 0, stream>>>(bufA, ei, ew, ioff, icsr, b1, bufB, stats);
    k_bn_relu<<<gElem, 256, 0, stream>>>(bufB, stats, g1, be1, bufC, (unsigned short*)0);

    // ---- GCN layer 2 ----
    k_gemm_ab<<<313, 256, 0, stream>>>(bufC, W2, bufA, NN, 128, 7);
    k_gather<<<NN / 8, 256, 0, stream>>>(bufA, ei, ew, ioff, icsr, b2, bufB, stats + 256);
    k_bn_relu<<<gElem, 256, 0, stream>>>(bufB, stats + 256, g2, be2, bufC, cbf);

    // ---- LSTM input projections: bf16 MFMA, both dirs, permuted [t][f][gate] ----
    dim3 gmm(157, 2);
    k_mm512p<<<gmm, 256, 0, stream>>>(cbf, wfbf, wbbf, bsumf, bsumb, Xf, Xb);

    // ---- sequential bidirectional scan (R5 structure) ----
    k_lstm<<<2, 512, 0, stream>>>(Xf, Xb, Whhf, Whhb, hfp, hbp);

    // ---- attention is identity; final matmul ----
    k_out<<<(NN * 12 + 255) / 256, 256, 0, stream>>>(hfp, hbp, Wo, bo, out);
}